// Round 4
// baseline (118.725 us; speedup 1.0000x reference)
//
#include <hip/hip_runtime.h>
#include <hip/hip_bf16.h>

// RingConv2d via f16 MFMA implicit GEMM, barrier-free conv.
// out[b,o,i,j] = sum_{c,kh,kw} cos(xpad - w): cos(a-b)=cos a cos b + sin a sin b
// GEMM: M=o(128), N=px(32*64*64), K=1152 = 4 cgroups x 9 taps x (16c x 2trig)
// MFMA 16x16x32_f16 lane k-map: k = {4g+j (j<4), 16+4g+(j-4)}, g=lane>>4
// x prepped to PADDED [b][cg][66][66] pixels of 64B (16c x (cos,sin) f16);
// border = (1,0) so no bounds checks in conv. No LDS, no __syncthreads.

typedef _Float16 half8 __attribute__((ext_vector_type(8)));
typedef float f32x4 __attribute__((ext_vector_type(4)));

#define NB 32
#define NC 64
#define NH 64
#define NW 64
#define NO 128
#define PW 66   // padded tile width/height in pixels

union U16 { unsigned short u; _Float16 h; };
union HB { uint4 u4; unsigned long long q[2]; half8 h; };

__device__ inline unsigned pack_cs(float ang) {
    float s, c;
    sincosf(ang, &s, &c);
    U16 uc, us; uc.h = (_Float16)c; us.h = (_Float16)s;
    return (unsigned)uc.u | ((unsigned)us.u << 16);   // cos low, sin high
}

__device__ inline unsigned pack_cs_fast(float ang) {
    float s, c;
    __sincosf(ang, &s, &c);
    U16 uc, us; uc.h = (_Float16)c; us.h = (_Float16)s;
    return (unsigned)uc.u | ((unsigned)us.u << 16);
}

// ---- prep x: [b][c][h][w] f32 -> xp[b][cg][1+row][1+col] 64B pixel
__global__ __launch_bounds__(256) void prep_x(const float* __restrict__ x,
                                              uint4* __restrict__ xp) {
    __shared__ unsigned ls[64 * 65];
    const int b = blockIdx.x >> 6, row = blockIdx.x & 63;
    const int t = threadIdx.x;
#pragma unroll
    for (int pass = 0; pass < 16; ++pass) {
        int c = pass * 4 + (t >> 6);
        int col = t & 63;
        float v = x[((size_t)(b * NC + c) * NH + row) * NW + col];
        ls[c * 65 + col] = pack_cs_fast(v);
    }
    __syncthreads();
    const int q = t & 3, col = t >> 2;          // col 0..63
#pragma unroll
    for (int cg = 0; cg < 4; ++cg) {
        uint4 vv;
        vv.x = ls[(cg * 16 + 4 * q + 0) * 65 + col];
        vv.y = ls[(cg * 16 + 4 * q + 1) * 65 + col];
        vv.z = ls[(cg * 16 + 4 * q + 2) * 65 + col];
        vv.w = ls[(cg * 16 + 4 * q + 3) * 65 + col];
        xp[(size_t)(((b * 4 + cg) * PW + row + 1) * PW + col + 1) * 4 + q] = vv;
    }
}

// ---- fill padded border pixels with (cos,sin)=(1,0)
__global__ __launch_bounds__(256) void prep_border(uint4* __restrict__ xp) {
    const int bc = blockIdx.x;                  // 0..127 = b*4+cg
    uint4* base = xp + (size_t)bc * PW * PW * 4;
    const uint4 v = make_uint4(0x3C00u, 0x3C00u, 0x3C00u, 0x3C00u);
    for (int idx = threadIdx.x; idx < 260 * 4; idx += 256) {
        int p = idx >> 2, q = idx & 3;
        int r, c;
        if (p < 66)       { r = 0;       c = p; }
        else if (p < 132) { r = 65;      c = p - 66; }
        else if (p < 196) { r = p - 131; c = 0; }     // r = 1..64
        else              { r = p - 195; c = 65; }    // r = 1..64
        base[(size_t)(r * PW + c) * 4 + q] = v;
    }
}

// ---- prep w: OIHW f32 -> wq[chunk36][o128][g4] 16B = A-fragment order
__global__ __launch_bounds__(256) void prep_w(const float* __restrict__ w,
                                              uint4* __restrict__ wq) {
    int t = blockIdx.x * 256 + threadIdx.x;     // 36*128*4 = 18432
    if (t >= 36 * 128 * 4) return;
    int g = t & 3, o = (t >> 2) & 127, chunk = t >> 9;
    int cg = chunk / 9, kpos = chunk % 9, kh = kpos / 3, kw = kpos % 3;
    unsigned r[4];
#pragma unroll
    for (int m = 0; m < 4; ++m) {
        int c_sub = (m < 2) ? (2 * g + m) : (8 + 2 * g + (m - 2));
        int c = cg * 16 + c_sub;
        float ang = w[((o * NC + c) * 3 + kh) * 3 + kw];
        r[m] = pack_cs(ang);
    }
    wq[t] = make_uint4(r[0], r[1], r[2], r[3]);
}

// ---- conv: block = 16x16 px x 64 o, 4 waves; barrier-free, loads from padded xp
__global__ __launch_bounds__(256, 4) void ring_conv(const uint4* __restrict__ xp,
                                                    const uint4* __restrict__ wq,
                                                    float* __restrict__ out) {
    const int ob = blockIdx.x & 1;            // o base 0/64
    const int pxb = blockIdx.x >> 1;          // 512 pixel blocks
    const int jt = pxb & 3, itile = (pxb >> 2) & 3, b = pxb >> 4;
    const int row0 = itile * 16, col0 = jt * 16;

    const int t = threadIdx.x, lane = t & 63, wid = t >> 6;
    const int l15 = lane & 15, g = lane >> 4;

    f32x4 acc[4][4] = {};                      // [px-row r][o-frag f]

    for (int cg = 0; cg < 4; ++cg) {
        // per-lane base: pixel (row0+wid*4, col0+l15) at r=kh=kw=0, byte g*8
        const char* xb = (const char*)xp
            + ((size_t)(b * 4 + cg) * PW * PW
               + (size_t)((row0 + wid * 4) * PW + col0 + l15)) * 64 + g * 8;
        const uint4* wb = wq + (size_t)(cg * 9) * 128 * 4 + (ob * 64 + l15) * 4 + g;

#pragma unroll
        for (int kpos = 0; kpos < 9; ++kpos) {
            const int kh = kpos / 3, kw = kpos % 3;
            HB A[4];
#pragma unroll
            for (int f = 0; f < 4; ++f)
                A[f].u4 = wb[kpos * 512 + f * 64];
#pragma unroll
            for (int r = 0; r < 4; ++r) {
                const char* sp = xb + ((r + kh) * PW + kw) * 64;
                HB Bv;
                Bv.q[0] = *(const unsigned long long*)sp;         // k = 4g+0..3
                Bv.q[1] = *(const unsigned long long*)(sp + 32);  // k = 16+4g+0..3
#pragma unroll
                for (int f = 0; f < 4; ++f)
                    acc[r][f] = __builtin_amdgcn_mfma_f32_16x16x32_f16(A[f].h, Bv.h,
                                                                       acc[r][f], 0, 0, 0);
            }
        }
    }

    // epilogue: D col = l15 = px col, row = 4g+i = o within frag
#pragma unroll
    for (int r = 0; r < 4; ++r) {
        int orow = row0 + wid * 4 + r;
#pragma unroll
        for (int f = 0; f < 4; ++f) {
            int o0 = ob * 64 + f * 16 + 4 * g;
            float* p = out + (((size_t)b * NO + o0) * NH + orow) * NW + col0 + l15;
#pragma unroll
            for (int i = 0; i < 4; ++i)
                p[(size_t)i * NH * NW] = acc[r][f][i];
        }
    }
}

extern "C" void kernel_launch(void* const* d_in, const int* in_sizes, int n_in,
                              void* d_out, int out_size, void* d_ws, size_t ws_size,
                              hipStream_t stream) {
    const float* x = (const float*)d_in[0];
    const float* w = (const float*)d_in[1];

    // xp: 32*4*66*66*64B = 35.7 MB ; wq after it
    uint4* xpnt = (uint4*)d_ws;
    uint4* wqp = (uint4*)((char*)d_ws + (size_t)36 * 1024 * 1024);

    prep_border<<<NB * 4, 256, 0, stream>>>(xpnt);
    prep_x<<<NB * NH, 256, 0, stream>>>(x, xpnt);
    prep_w<<<72, 256, 0, stream>>>(w, wqp);
    ring_conv<<<1024, 256, 0, stream>>>(xpnt, wqp, (float*)d_out);
}

// Round 5
// 83.789 us; speedup vs baseline: 1.4169x; 1.4169x over previous
//
#include <hip/hip_runtime.h>
#include <hip/hip_bf16.h>

// RingConv2d via f16 MFMA implicit GEMM, double-buffered LDS pipeline.
// out[b,o,i,j] = sum_{c,kh,kw} cos(xpad - w): cos(a-b)=cos a cos b + sin a sin b
// GEMM: M=o(128), N=px(32*64*64), K=1152 = 4 cgroups x 9 taps x (16c x 2trig)
// MFMA 16x16x32_f16 lane k-map: k = {4g+j (j<4), 16+4g+(j-4)}, g=lane>>4
// x prepped PADDED [b][cg][66][66] pixels of 64B; border=(cos,sin)=(1,0).

typedef _Float16 half8 __attribute__((ext_vector_type(8)));
typedef float f32x4 __attribute__((ext_vector_type(4)));

#define NB 32
#define NC 64
#define NH 64
#define NW 64
#define NO 128
#define PW 66

union U16 { unsigned short u; _Float16 h; };
union HB { uint4 u4; unsigned long long q[2]; half8 h; };

__device__ inline unsigned pack_cs(float ang) {
    float s, c;
    sincosf(ang, &s, &c);
    U16 uc, us; uc.h = (_Float16)c; us.h = (_Float16)s;
    return (unsigned)uc.u | ((unsigned)us.u << 16);   // cos low, sin high
}

__device__ inline unsigned pack_cs_fast(float ang) {
    float s, c;
    __sincosf(ang, &s, &c);
    U16 uc, us; uc.h = (_Float16)c; us.h = (_Float16)s;
    return (unsigned)uc.u | ((unsigned)us.u << 16);
}

// ---- prep x: [b][c][h][w] f32 -> xp[b][cg][1+row][1+col] 64B pixel
__global__ __launch_bounds__(256) void prep_x(const float* __restrict__ x,
                                              uint4* __restrict__ xp) {
    __shared__ unsigned ls[64 * 65];
    const int b = blockIdx.x >> 6, row = blockIdx.x & 63;
    const int t = threadIdx.x;
#pragma unroll
    for (int pass = 0; pass < 16; ++pass) {
        int c = pass * 4 + (t >> 6);
        int col = t & 63;
        float v = x[((size_t)(b * NC + c) * NH + row) * NW + col];
        ls[c * 65 + col] = pack_cs_fast(v);
    }
    __syncthreads();
    const int q = t & 3, col = t >> 2;
#pragma unroll
    for (int cg = 0; cg < 4; ++cg) {
        uint4 vv;
        vv.x = ls[(cg * 16 + 4 * q + 0) * 65 + col];
        vv.y = ls[(cg * 16 + 4 * q + 1) * 65 + col];
        vv.z = ls[(cg * 16 + 4 * q + 2) * 65 + col];
        vv.w = ls[(cg * 16 + 4 * q + 3) * 65 + col];
        xp[(size_t)(((b * 4 + cg) * PW + row + 1) * PW + col + 1) * 4 + q] = vv;
    }
}

// ---- fill padded border pixels with (cos,sin)=(1,0)
__global__ __launch_bounds__(256) void prep_border(uint4* __restrict__ xp) {
    const int bc = blockIdx.x;                  // 0..127 = b*4+cg
    uint4* base = xp + (size_t)bc * PW * PW * 4;
    const uint4 v = make_uint4(0x3C00u, 0x3C00u, 0x3C00u, 0x3C00u);
    for (int idx = threadIdx.x; idx < 260 * 4; idx += 256) {
        int p = idx >> 2, q = idx & 3;
        int r, c;
        if (p < 66)       { r = 0;       c = p; }
        else if (p < 132) { r = 65;      c = p - 66; }
        else if (p < 196) { r = p - 131; c = 0; }
        else              { r = p - 195; c = 65; }
        base[(size_t)(r * PW + c) * 4 + q] = v;
    }
}

// ---- prep w: OIHW f32 -> wq[chunk36][o128][g4] 16B = A-fragment order
__global__ __launch_bounds__(256) void prep_w(const float* __restrict__ w,
                                              uint4* __restrict__ wq) {
    int t = blockIdx.x * 256 + threadIdx.x;     // 36*128*4 = 18432
    if (t >= 36 * 128 * 4) return;
    int g = t & 3, o = (t >> 2) & 127, chunk = t >> 9;
    int cg = chunk / 9, kpos = chunk % 9, kh = kpos / 3, kw = kpos % 3;
    unsigned r[4];
#pragma unroll
    for (int m = 0; m < 4; ++m) {
        int c_sub = (m < 2) ? (2 * g + m) : (8 + 2 * g + (m - 2));
        int c = cg * 16 + c_sub;
        float ang = w[((o * NC + c) * 3 + kh) * 3 + kw];
        r[m] = pack_cs(ang);
    }
    wq[t] = make_uint4(r[0], r[1], r[2], r[3]);
}

// ---- conv: block = 16x16 px x 64 o, 4 waves; double-buffered LDS pipeline
__global__ __launch_bounds__(256, 3) void ring_conv(const uint4* __restrict__ xp,
                                                    const uint4* __restrict__ wq,
                                                    float* __restrict__ out) {
    __shared__ __align__(16) char xs[2][324 * 72];   // 2 x 23328 B

    // chunked XCD swizzle: dispatch d -> orig block (d%8)*128 + d/8 (1024 = 128*8)
    const int d = blockIdx.x;
    const int blk = (d & 7) * 128 + (d >> 3);

    const int ob = blk & 1;                   // o base 0/64
    const int pxb = blk >> 1;
    const int jt = pxb & 3, itile = (pxb >> 2) & 3, b = pxb >> 4;
    const int row0 = itile * 16, col0 = jt * 16;

    const int t = threadIdx.x, lane = t & 63, wid = t >> 6;
    const int l15 = lane & 15, g = lane >> 4;

    f32x4 acc[4][4] = {};                      // [px-row r][o-frag f]

    // staging geometry: element e = k*256 + t ; pixel p=e>>2, quad q=e&3
    int goff[6], loff[6];
#pragma unroll
    for (int k = 0; k < 6; ++k) {
        int e = k * 256 + t;
        if (e > 1295) e = 1295;               // clamp tail (dup harmless)
        int p = e >> 2, q = e & 3;
        int rr = p / 18, cc = p % 18;
        goff[k] = ((row0 + rr) * PW + (col0 + cc)) * 4 + q;
        loff[k] = p * 72 + q * 16;
    }
    const bool tail = (t < 16);
    const size_t img_stride = (size_t)PW * PW * 4;          // uint4 per (b,cg)
    const uint4* img0 = xp + (size_t)(b * 4) * img_stride;

    // prologue: stage cg0 -> buf0
    {
        uint4 S[6];
#pragma unroll
        for (int k = 0; k < 5; ++k) S[k] = img0[goff[k]];
        if (tail) S[5] = img0[goff[5]];
#pragma unroll
        for (int k = 0; k < 5; ++k) *(uint4*)&xs[0][loff[k]] = S[k];
        if (tail) *(uint4*)&xs[0][loff[5]] = S[5];
    }
    __syncthreads();

    const uint4* wb = wq + (size_t)(ob * 64 + l15) * 4 + g;

    for (int cg = 0; cg < 4; ++cg) {
        const int cur = cg & 1;
        const char* xbuf = xs[cur];
        const uint4* wcg = wb + (size_t)(cg * 9) * 512;

        // A lookahead depth 2 (issued BEFORE stage loads -> early consumes
        // don't drain the stage per vmcnt FIFO order)
        HB A[2][4];
#pragma unroll
        for (int f = 0; f < 4; ++f) A[0][f].u4 = wcg[0 * 512 + f * 64];
#pragma unroll
        for (int f = 0; f < 4; ++f) A[1][f].u4 = wcg[1 * 512 + f * 64];

        // issue stage loads for cg+1 (in flight across the whole compute)
        uint4 S[6];
        if (cg < 3) {
            const uint4* img = img0 + (size_t)(cg + 1) * img_stride;
#pragma unroll
            for (int k = 0; k < 5; ++k) S[k] = img[goff[k]];
            if (tail) S[5] = img[goff[5]];
        }

#pragma unroll
        for (int kpos = 0; kpos < 9; ++kpos) {
            const int kh = kpos / 3, kw = kpos % 3;
            HB* Ac = A[kpos & 1];
#pragma unroll
            for (int r = 0; r < 4; ++r) {
                int pix = (wid * 4 + r + kh) * 18 + l15 + kw;
                const char* sp = xbuf + pix * 72 + g * 8;
                HB Bv;
                Bv.q[0] = *(const unsigned long long*)sp;         // k = 4g+0..3
                Bv.q[1] = *(const unsigned long long*)(sp + 32);  // k = 16+4g+0..3
#pragma unroll
                for (int f = 0; f < 4; ++f)
                    acc[r][f] = __builtin_amdgcn_mfma_f32_16x16x32_f16(Ac[f].h, Bv.h,
                                                                       acc[r][f], 0, 0, 0);
            }
            if (kpos < 7) {   // refill consumed slot with A(kpos+2)
#pragma unroll
                for (int f = 0; f < 4; ++f) Ac[f].u4 = wcg[(kpos + 2) * 512 + f * 64];
            }
        }

        if (cg < 3) {         // write staged regs into the other buffer
            char* dst = xs[cur ^ 1];
#pragma unroll
            for (int k = 0; k < 5; ++k) *(uint4*)&dst[loff[k]] = S[k];
            if (tail) *(uint4*)&dst[loff[5]] = S[5];
        }
        __syncthreads();
    }

    // epilogue: D col = l15 = px col, row = 4g+i = o within frag
#pragma unroll
    for (int r = 0; r < 4; ++r) {
        int orow = row0 + wid * 4 + r;
#pragma unroll
        for (int f = 0; f < 4; ++f) {
            int o0 = ob * 64 + f * 16 + 4 * g;
            float* p = out + (((size_t)b * NO + o0) * NH + orow) * NW + col0 + l15;
#pragma unroll
            for (int i = 0; i < 4; ++i)
                p[(size_t)i * NH * NW] = acc[r][f][i];
        }
    }
}

extern "C" void kernel_launch(void* const* d_in, const int* in_sizes, int n_in,
                              void* d_out, int out_size, void* d_ws, size_t ws_size,
                              hipStream_t stream) {
    const float* x = (const float*)d_in[0];
    const float* w = (const float*)d_in[1];

    uint4* xpnt = (uint4*)d_ws;                                  // 35.7 MB padded
    uint4* wqp = (uint4*)((char*)d_ws + (size_t)36 * 1024 * 1024);

    prep_border<<<NB * 4, 256, 0, stream>>>(xpnt);
    prep_x<<<NB * NH, 256, 0, stream>>>(x, xpnt);
    prep_w<<<72, 256, 0, stream>>>(w, wqp);
    ring_conv<<<1024, 256, 0, stream>>>(xpnt, wqp, (float*)d_out);
}